// Round 1
// baseline (472.228 us; speedup 1.0000x reference)
//
#include <hip/hip_runtime.h>
#include <stdint.h>

#define B_   8
#define C_   256
#define T_   8192
#define TOUT 8190

typedef float  f32x4  __attribute__((ext_vector_type(4)));
typedef __bf16 bf16x8 __attribute__((ext_vector_type(8)));

// ws layout (bytes)
#define W1_OFF 0              // 512x1536 bf16, fragment-packed: 1572864 B
#define W2_OFF 1572864        // 512x256  bf16, fragment-packed:  262144 B
#define B1_OFF 1835008        // 512 f32 stage-1 bias (f/g interleaved)
#define B2_OFF 1837056        // 512 f32 stage-2 bias (res, skip)
#define N_W1 (512 * 1536)
#define N_W2 (512 * 256)

static __device__ __forceinline__ unsigned short f2bf(float x) {
  union { float f; uint32_t u; } v; v.f = x;
  uint32_t r = v.u + 0x7fffu + ((v.u >> 16) & 1u);   // RNE
  return (unsigned short)(r >> 16);
}

// Pack weights into MFMA A-fragment order: frag_id = kf*NMF + mf,
// within frag: lane = (kq*16 + (m&15)), elem j -> k = kf*32 + kq*8 + j.
// W1 rows interleaved: row 2c = filter(tanh) ch c, row 2c+1 = gate ch c.
// W1 k = src*512 + c_in*2 + tap  (src: 0=x,1=cin,2=gin).
__global__ __launch_bounds__(256) void prep_kernel(
    const float* w_fx, const float* w_fc, const float* w_fg,
    const float* w_gx, const float* w_gc, const float* w_gg,
    const float* b_fx, const float* b_fc, const float* b_fg,
    const float* b_gx, const float* b_gc, const float* b_gg,
    const float* w_res, const float* b_res,
    const float* w_skip, const float* b_skip,
    char* ws) {
  int idx = blockIdx.x * 256 + threadIdx.x;
  unsigned short* w1p = (unsigned short*)(ws + W1_OFF);
  unsigned short* w2p = (unsigned short*)(ws + W2_OFF);
  float* bias1 = (float*)(ws + B1_OFF);
  float* bias2 = (float*)(ws + B2_OFF);
  if (idx < N_W1) {
    int m = idx / 1536, k = idx - m * 1536;
    int src = k >> 9, rem = k & 511, ci = rem >> 1, tap = rem & 1;
    int cout = m >> 1, br = m & 1;
    const float* wp = (br == 0) ? (src == 0 ? w_fx : (src == 1 ? w_fc : w_fg))
                                : (src == 0 ? w_gx : (src == 1 ? w_gc : w_gg));
    float val = wp[cout * 512 + ci * 2 + tap];
    int mf = m >> 4, ml = m & 15, kf = k >> 5, kl = k & 31, kq = kl >> 3, j = kl & 7;
    w1p[(size_t)(kf * 32 + mf) * 512 + (kq * 16 + ml) * 8 + j] = f2bf(val);
  } else if (idx < N_W1 + N_W2) {
    int i2 = idx - N_W1;
    int m = i2 >> 8, k = i2 & 255;   // rows 0..255 = w_res, 256..511 = w_skip
    float val = (m < 256) ? w_res[m * 256 + k] : w_skip[(m - 256) * 256 + k];
    int mf = m >> 4, ml = m & 15, kf = k >> 5, kl = k & 31, kq = kl >> 3, j = kl & 7;
    w2p[(size_t)(kf * 32 + mf) * 512 + (kq * 16 + ml) * 8 + j] = f2bf(val);
  } else if (idx < N_W1 + N_W2 + 1024) {
    int i3 = idx - N_W1 - N_W2;
    if (i3 < 512) {
      int c = i3 >> 1;
      bias1[i3] = (i3 & 1) ? (b_gx[c] + b_gc[c] + b_gg[c])
                           : (b_fx[c] + b_fc[c] + b_fg[c]);
    } else {
      int m = i3 - 512;
      bias2[m] = (m < 256) ? b_res[m] : b_skip[m - 256];
    }
  }
}

// One block = (batch b, 64-wide time tile). Stage1: 512x64 = W1(512x1536)*Z.
// Stage2: 512x64 = W2(512x256)*Y, Y block-local in LDS. 4 waves, wave w owns
// rows [w*128, w*128+128) of both stages (acc 8x4 frags = 128 VGPR).
__global__ __launch_bounds__(256, 2) void wavenet_kernel(
    const float* __restrict__ x, const float* __restrict__ cin,
    const float* __restrict__ gin, const float* __restrict__ skips,
    const char* __restrict__ ws, float* __restrict__ out) {
  __shared__ short Zb[64 * 72];    // [n][72]: 64 k-shorts + 8 pad (16B-aligned rows)
  __shared__ short Yb[64 * 256];   // [n][256] bf16, byte ^= (n&7)<<4 swizzle

  const unsigned short* w1p = (const unsigned short*)(ws + W1_OFF);
  const unsigned short* w2p = (const unsigned short*)(ws + W2_OFF);
  const float* bias1 = (const float*)(ws + B1_OFF);
  const float* bias2 = (const float*)(ws + B2_OFF);

  const int tid = threadIdx.x;
  const int w = tid >> 6, lane = tid & 63, ln = lane & 15, kq = lane >> 4;
  const int bb = blockIdx.x >> 7, tile = blockIdx.x & 127;
  const int t0 = tile * 64;
  const int valid = min(64, TOUT - t0);   // 62 on the last tile

  float* out0 = out;                                 // res
  float* out1 = out + (size_t)B_ * C_ * TOUT;        // cin slice
  float* out2 = out + 2 * (size_t)B_ * C_ * TOUT;    // gin slice
  float* out3 = out + 3 * (size_t)B_ * C_ * TOUT;    // skips_out

  f32x4 acc[8][4];
#pragma unroll
  for (int i = 0; i < 8; ++i)
#pragma unroll
    for (int j = 0; j < 4; ++j) acc[i][j] = (f32x4){0.f, 0.f, 0.f, 0.f};

  const int sn = tid >> 2;              // staging: n = 0..63
  const int scc = tid & 3;              // staging: channel-sub 0..3
  const int t = t0 + sn;
  const int t2 = min(t + 2, T_ - 1);    // clamp; cols >= valid are masked later

  // ---- stage 1: K loop, 24 chunks of 64 k (32 channels x 2 taps) ----
  for (int chunk = 0; chunk < 24; ++chunk) {
    const int s = chunk >> 3;
    const float* src = (s == 0) ? x : (s == 1) ? cin : gin;
    float* cpy = (s == 0) ? (float*)0 : (s == 1) ? out1 : out2;
    const int c0 = (chunk & 7) * 32;
    __syncthreads();
#pragma unroll
    for (int it = 0; it < 8; ++it) {
      int cc = scc + it * 4;
      int c = c0 + cc;
      const float* p = src + ((size_t)(bb * C_ + c)) * T_;
      float a0 = p[t], a1 = p[t2];
      uint32_t pk = (uint32_t)f2bf(a0) | ((uint32_t)f2bf(a1) << 16);
      *(uint32_t*)&Zb[sn * 72 + cc * 2] = pk;
      // free cin/gin slice copy (exact fp32, from the tap-1 register)
      if (cpy && sn < valid) cpy[((size_t)(bb * C_ + c)) * TOUT + t0 + sn] = a1;
    }
    __syncthreads();
#pragma unroll
    for (int kf = 0; kf < 2; ++kf) {
      bf16x8 zf[4];
#pragma unroll
      for (int ni = 0; ni < 4; ++ni)
        zf[ni] = *(const bf16x8*)&Zb[(ni * 16 + ln) * 72 + kf * 32 + kq * 8];
#pragma unroll
      for (int mi = 0; mi < 8; ++mi) {
        const bf16x8 wf = *(const bf16x8*)
            &w1p[(size_t)((chunk * 2 + kf) * 32 + (w * 8 + mi)) * 512 + lane * 8];
#pragma unroll
        for (int ni = 0; ni < 4; ++ni)
          acc[mi][ni] = __builtin_amdgcn_mfma_f32_16x16x32_bf16(wf, zf[ni], acc[mi][ni], 0, 0, 0);
      }
    }
  }

  // ---- epilogue 1: bias + tanh*sigmoid -> Yb (bf16, swizzled) ----
#pragma unroll
  for (int mi = 0; mi < 8; ++mi) {
    const int mbase = w * 128 + mi * 16 + kq * 4;    // multiple of 4
    const f32x4 b4 = *(const f32x4*)&bias1[mbase];
    const int cy0 = mbase >> 1;                      // even y-channel
#pragma unroll
    for (int ni = 0; ni < 4; ++ni) {
      f32x4 v = acc[mi][ni];
      float f0 = v.x + b4.x, g0 = v.y + b4.y, f1 = v.z + b4.z, g1 = v.w + b4.w;
      float y0 = (2.f / (1.f + __expf(-2.f * f0)) - 1.f) * (1.f / (1.f + __expf(-g0)));
      float y1 = (2.f / (1.f + __expf(-2.f * f1)) - 1.f) * (1.f / (1.f + __expf(-g1)));
      int n = ni * 16 + ln;
      uint32_t pk = (uint32_t)f2bf(y0) | ((uint32_t)f2bf(y1) << 16);
      int boff = (n * 512 + cy0 * 2) ^ ((n & 7) << 4);
      *(uint32_t*)((char*)Yb + boff) = pk;
    }
  }
  __syncthreads();

  // ---- stage 2: [res;skip] = W2 * Y ----
  f32x4 acc2[8][4];
#pragma unroll
  for (int i = 0; i < 8; ++i)
#pragma unroll
    for (int j = 0; j < 4; ++j) acc2[i][j] = (f32x4){0.f, 0.f, 0.f, 0.f};

#pragma unroll
  for (int kf = 0; kf < 8; ++kf) {
    bf16x8 zf[4];
#pragma unroll
    for (int ni = 0; ni < 4; ++ni) {
      int n = ni * 16 + ln;
      int boff = (n * 512 + (kf * 32 + kq * 8) * 2) ^ ((n & 7) << 4);
      zf[ni] = *(const bf16x8*)((char*)Yb + boff);
    }
#pragma unroll
    for (int mi = 0; mi < 8; ++mi) {
      const bf16x8 wf = *(const bf16x8*)
          &w2p[(size_t)(kf * 32 + (w * 8 + mi)) * 512 + lane * 8];
#pragma unroll
      for (int ni = 0; ni < 4; ++ni)
        acc2[mi][ni] = __builtin_amdgcn_mfma_f32_16x16x32_bf16(wf, zf[ni], acc2[mi][ni], 0, 0, 0);
    }
  }

  // ---- epilogue 2: bias + residual adds, store res / skips_out ----
#pragma unroll
  for (int mi = 0; mi < 8; ++mi) {
    const int mbase = w * 128 + mi * 16 + kq * 4;
    const f32x4 b4 = *(const f32x4*)&bias2[mbase];
#pragma unroll
    for (int r = 0; r < 4; ++r) {
      const int m2 = mbase + r;
      const int isres = (m2 < 256);           // uniform per wave (w<2)
      const int crow = isres ? m2 : m2 - 256;
      const float* ap = (isres ? x : skips) + ((size_t)(bb * C_ + crow)) * T_ + t0 + 2;
      float* dp = (isres ? out0 : out3) + ((size_t)(bb * C_ + crow)) * TOUT + t0;
      const float bs = b4[r];
#pragma unroll
      for (int ni = 0; ni < 4; ++ni) {
        int n = ni * 16 + ln;
        if (n < valid) dp[n] = acc2[mi][ni][r] + bs + ap[n];
      }
    }
  }
}

extern "C" void kernel_launch(void* const* d_in, const int* in_sizes, int n_in,
                              void* d_out, int out_size, void* d_ws, size_t ws_size,
                              hipStream_t stream) {
  const float* xx    = (const float*)d_in[0];
  const float* cin   = (const float*)d_in[1];
  const float* gin   = (const float*)d_in[2];
  const float* skips = (const float*)d_in[3];
  const float* w_fx = (const float*)d_in[4],  *b_fx = (const float*)d_in[5];
  const float* w_fc = (const float*)d_in[6],  *b_fc = (const float*)d_in[7];
  const float* w_fg = (const float*)d_in[8],  *b_fg = (const float*)d_in[9];
  const float* w_gx = (const float*)d_in[10], *b_gx = (const float*)d_in[11];
  const float* w_gc = (const float*)d_in[12], *b_gc = (const float*)d_in[13];
  const float* w_gg = (const float*)d_in[14], *b_gg = (const float*)d_in[15];
  const float* w_res  = (const float*)d_in[16], *b_res  = (const float*)d_in[17];
  const float* w_skip = (const float*)d_in[18], *b_skip = (const float*)d_in[19];
  char* ws = (char*)d_ws;
  float* outp = (float*)d_out;

  // pack weights/biases into ws (runs every call; deterministic)
  prep_kernel<<<(N_W1 + N_W2 + 1024) / 256, 256, 0, stream>>>(
      w_fx, w_fc, w_fg, w_gx, w_gc, w_gg,
      b_fx, b_fc, b_fg, b_gx, b_gc, b_gg,
      w_res, b_res, w_skip, b_skip, ws);

  // 8 batches x 128 time-tiles of 64
  wavenet_kernel<<<1024, 256, 0, stream>>>(xx, cin, gin, skips, ws, outp);
}

// Round 2
// 338.039 us; speedup vs baseline: 1.3970x; 1.3970x over previous
//
#include <hip/hip_runtime.h>
#include <stdint.h>

#define B_   8
#define C_   256
#define T_   8192
#define TOUT 8190

typedef float  f32x4  __attribute__((ext_vector_type(4)));
typedef float  f32x2  __attribute__((ext_vector_type(2)));
typedef __bf16 bf16x8 __attribute__((ext_vector_type(8)));

// ws layout (bytes)
#define W1_OFF 0              // 512x1536 bf16, fragment-packed: 1572864 B
#define W2_OFF 1572864        // 512x256  bf16, fragment-packed:  262144 B
#define B1_OFF 1835008        // 512 f32 stage-1 bias (f/g interleaved)
#define B2_OFF 1837056        // 512 f32 stage-2 bias (res, skip)
#define N_W1 (512 * 1536)
#define N_W2 (512 * 256)

static __device__ __forceinline__ unsigned short f2bf(float x) {
  union { float f; uint32_t u; } v; v.f = x;
  uint32_t r = v.u + 0x7fffu + ((v.u >> 16) & 1u);   // RNE
  return (unsigned short)(r >> 16);
}

// Pack weights into MFMA A-fragment order: frag_id = kf*32 + mf,
// within frag: lane = (kq*16 + (m&15)), elem j -> k = kf*32 + kq*8 + j.
// W1 rows interleaved: row 2c = filter(tanh) ch c, row 2c+1 = gate ch c.
// W1 k = src*512 + c_in*2 + tap  (src: 0=x,1=cin,2=gin).
__global__ __launch_bounds__(256) void prep_kernel(
    const float* w_fx, const float* w_fc, const float* w_fg,
    const float* w_gx, const float* w_gc, const float* w_gg,
    const float* b_fx, const float* b_fc, const float* b_fg,
    const float* b_gx, const float* b_gc, const float* b_gg,
    const float* w_res, const float* b_res,
    const float* w_skip, const float* b_skip,
    char* ws) {
  int idx = blockIdx.x * 256 + threadIdx.x;
  unsigned short* w1p = (unsigned short*)(ws + W1_OFF);
  unsigned short* w2p = (unsigned short*)(ws + W2_OFF);
  float* bias1 = (float*)(ws + B1_OFF);
  float* bias2 = (float*)(ws + B2_OFF);
  if (idx < N_W1) {
    int m = idx / 1536, k = idx - m * 1536;
    int src = k >> 9, rem = k & 511, ci = rem >> 1, tap = rem & 1;
    int cout = m >> 1, br = m & 1;
    const float* wp = (br == 0) ? (src == 0 ? w_fx : (src == 1 ? w_fc : w_fg))
                                : (src == 0 ? w_gx : (src == 1 ? w_gc : w_gg));
    float val = wp[cout * 512 + ci * 2 + tap];
    int mf = m >> 4, ml = m & 15, kf = k >> 5, kl = k & 31, kq = kl >> 3, j = kl & 7;
    w1p[(size_t)(kf * 32 + mf) * 512 + (kq * 16 + ml) * 8 + j] = f2bf(val);
  } else if (idx < N_W1 + N_W2) {
    int i2 = idx - N_W1;
    int m = i2 >> 8, k = i2 & 255;   // rows 0..255 = w_res, 256..511 = w_skip
    float val = (m < 256) ? w_res[m * 256 + k] : w_skip[(m - 256) * 256 + k];
    int mf = m >> 4, ml = m & 15, kf = k >> 5, kl = k & 31, kq = kl >> 3, j = kl & 7;
    w2p[(size_t)(kf * 32 + mf) * 512 + (kq * 16 + ml) * 8 + j] = f2bf(val);
  } else if (idx < N_W1 + N_W2 + 1024) {
    int i3 = idx - N_W1 - N_W2;
    if (i3 < 512) {
      int c = i3 >> 1;
      bias1[i3] = (i3 & 1) ? (b_gx[c] + b_gc[c] + b_gg[c])
                           : (b_fx[c] + b_fc[c] + b_fg[c]);
    } else {
      int m = i3 - 512;
      bias2[m] = (m < 256) ? b_res[m] : b_skip[m - 256];
    }
  }
}

// One block = (batch b, 64-wide time tile). 512 threads / 8 waves.
// Stage1: 512x64 = W1(512x1536)*Z, K split in 12 chunks of 128 k
// (64 channels x 2 taps). Wave w owns rows [w*64, w*64+64) -> acc[4][4].
// Z double-buffered in LDS, T14 split: issue loads(i+1), MFMA(i), write(i+1).
// Stage2: [res;skip](512x64) = W2(512x256)*Y, Y in LDS (reuses Z memory).
__global__ __launch_bounds__(512, 4) void wavenet_kernel(
    const float* __restrict__ x, const float* __restrict__ cin,
    const float* __restrict__ gin, const float* __restrict__ skips,
    const char* __restrict__ ws, float* __restrict__ out) {
  // union: Z double-buffer 2*64*136*2B = 34816 B  |  Yb 64*512B = 32768 B
  __shared__ __align__(16) char smem[34816];
  short* Z0 = (short*)smem;          // [64 n][136] (128 k + 8 pad shorts)
  short* Z1 = Z0 + 64 * 136;
  char*  Yb = smem;                  // [64 n][256 ch] bf16, byte ^= (n&7)<<4

  const unsigned short* w1p = (const unsigned short*)(ws + W1_OFF);
  const unsigned short* w2p = (const unsigned short*)(ws + W2_OFF);
  const float* bias1 = (const float*)(ws + B1_OFF);
  const float* bias2 = (const float*)(ws + B2_OFF);

  const int tid = threadIdx.x;
  const int w = tid >> 6, lane = tid & 63, ln = lane & 15, kq = lane >> 4;
  const int bb = blockIdx.x >> 7, tile = blockIdx.x & 127;
  const int t0 = tile * 64;
  const int valid = min(64, TOUT - t0);   // 62 on the last tile
  const int tb = t0 + w * 8;              // staging t-octet base (sq == w)

  float* out0 = out;                                 // res
  float* out1 = out + (size_t)B_ * C_ * TOUT;        // cin slice
  float* out2 = out + 2 * (size_t)B_ * C_ * TOUT;    // gin slice
  float* out3 = out + 3 * (size_t)B_ * C_ * TOUT;    // skips_out

  f32x4 acc[4][4];
#pragma unroll
  for (int i = 0; i < 4; ++i)
#pragma unroll
    for (int j = 0; j < 4; ++j) acc[i][j] = (f32x4){0.f, 0.f, 0.f, 0.f};

  // ---- staging helpers (chunk ch: src = ch>>2, channel group = ch&3) ----
  // thread (lane=channel-in-group, w=t-octet): loads floats tb..tb+9 (3xf4,
  // clamped at row end on the last tile; clamped values only feed masked n).
  auto issue = [&](int ch, f32x4& A, f32x4& Bv, f32x4& Cv) {
    const int s = ch >> 2, c0 = (ch & 3) * 64;
    const float* src = (s == 0) ? x : (s == 1) ? cin : gin;
    const float* p = src + ((size_t)(bb * C_ + c0 + lane)) * T_;
    A  = *(const f32x4*)(p + min(tb,     T_ - 4));
    Bv = *(const f32x4*)(p + min(tb + 4, T_ - 4));
    Cv = *(const f32x4*)(p + min(tb + 8, T_ - 4));
  };
  auto writeZ = [&](int ch, short* Zb, const f32x4& A, const f32x4& Bv,
                    const f32x4& Cv) {
    float F[10] = {A.x, A.y, A.z, A.w, Bv.x, Bv.y, Bv.z, Bv.w, Cv.x, Cv.y};
    unsigned short bv[10];
#pragma unroll
    for (int j = 0; j < 10; ++j) bv[j] = f2bf(F[j]);
#pragma unroll
    for (int j = 0; j < 8; ++j) {
      uint32_t pk = (uint32_t)bv[j] | ((uint32_t)bv[j + 2] << 16);
      *(uint32_t*)&Zb[(w * 8 + j) * 136 + lane * 2] = pk;   // 256B/wave contig
    }
    const int s = ch >> 2, c0 = (ch & 3) * 64;
    if (s) {  // free cin/gin slice copy: out[t0+n] = src[t0+n+2], n=tb-t0+2j
      float* o = (s == 1 ? out1 : out2) + ((size_t)(bb * C_ + c0 + lane)) * TOUT + tb;
#pragma unroll
      for (int j = 0; j < 4; ++j) {
        if (tb + 2 * j + 1 < TOUT) {
          f32x2 v = {F[2 + 2 * j], F[3 + 2 * j]};
          *(f32x2*)(o + 2 * j) = v;    // 8B-aligned (row*TOUT+tb even)
        }
      }
    }
  };
  auto mfmaZ = [&](int ch, const short* Zb) {
    const int base = ch * 4;           // kfg = s*16 + g*4 + kf = ch*4 + kf
#pragma unroll
    for (int kf = 0; kf < 4; ++kf) {
      bf16x8 zfr[4];
#pragma unroll
      for (int ni = 0; ni < 4; ++ni)
        zfr[ni] = *(const bf16x8*)&Zb[(ni * 16 + ln) * 136 + kf * 32 + kq * 8];
#pragma unroll
      for (int mi = 0; mi < 4; ++mi) {
        const bf16x8 wf = *(const bf16x8*)
            &w1p[(size_t)((base + kf) * 32 + (w * 4 + mi)) * 512 + lane * 8];
#pragma unroll
        for (int ni = 0; ni < 4; ++ni)
          acc[mi][ni] = __builtin_amdgcn_mfma_f32_16x16x32_bf16(
              wf, zfr[ni], acc[mi][ni], 0, 0, 0);
      }
    }
  };

  // ---- stage 1: prologue + 12-chunk pipelined loop (1 barrier/chunk) ----
  {
    f32x4 A, Bv, Cv;
    issue(0, A, Bv, Cv);
    writeZ(0, Z0, A, Bv, Cv);
  }
  __syncthreads();
  for (int i = 0; i < 12; ++i) {
    f32x4 A, Bv, Cv;
    if (i < 11) issue(i + 1, A, Bv, Cv);          // loads in flight over MFMA
    mfmaZ(i, (i & 1) ? Z1 : Z0);
    if (i < 11) writeZ(i + 1, (i & 1) ? Z0 : Z1, A, Bv, Cv);
    __syncthreads();
  }

  // ---- epilogue 1: bias + tanh*sigmoid -> Yb (bf16, swizzled) ----
#pragma unroll
  for (int mi = 0; mi < 4; ++mi) {
    const int mbase = w * 64 + mi * 16 + kq * 4;   // multiple of 4
    const f32x4 b4 = *(const f32x4*)&bias1[mbase];
#pragma unroll
    for (int ni = 0; ni < 4; ++ni) {
      f32x4 v = acc[mi][ni];
      float f0 = v.x + b4.x, g0 = v.y + b4.y, f1 = v.z + b4.z, g1 = v.w + b4.w;
      float y0 = (2.f / (1.f + __expf(-2.f * f0)) - 1.f) * (1.f / (1.f + __expf(-g0)));
      float y1 = (2.f / (1.f + __expf(-2.f * f1)) - 1.f) * (1.f / (1.f + __expf(-g1)));
      int n = ni * 16 + ln;
      uint32_t pk = (uint32_t)f2bf(y0) | ((uint32_t)f2bf(y1) << 16);
      int boff = (n * 512 + mbase) ^ ((n & 7) << 4);   // ch pair at byte mbase
      *(uint32_t*)(Yb + boff) = pk;
    }
  }
  __syncthreads();

  // ---- stage 2: [res;skip] = W2 * Y ----
  f32x4 acc2[4][4];
#pragma unroll
  for (int i = 0; i < 4; ++i)
#pragma unroll
    for (int j = 0; j < 4; ++j) acc2[i][j] = (f32x4){0.f, 0.f, 0.f, 0.f};

#pragma unroll
  for (int kf = 0; kf < 8; ++kf) {
    bf16x8 zfr[4];
#pragma unroll
    for (int ni = 0; ni < 4; ++ni) {
      int n = ni * 16 + ln;
      int boff = (n * 512 + kf * 64 + kq * 16) ^ ((n & 7) << 4);
      zfr[ni] = *(const bf16x8*)(Yb + boff);
    }
#pragma unroll
    for (int mi = 0; mi < 4; ++mi) {
      const bf16x8 wf = *(const bf16x8*)
          &w2p[(size_t)(kf * 32 + (w * 4 + mi)) * 512 + lane * 8];
#pragma unroll
      for (int ni = 0; ni < 4; ++ni)
        acc2[mi][ni] = __builtin_amdgcn_mfma_f32_16x16x32_bf16(
            wf, zfr[ni], acc2[mi][ni], 0, 0, 0);
    }
  }

  // ---- epilogue 2: bias + residual adds, store res / skips_out ----
#pragma unroll
  for (int mi = 0; mi < 4; ++mi) {
    const int mbase = w * 64 + mi * 16 + kq * 4;
    const f32x4 b4 = *(const f32x4*)&bias2[mbase];
#pragma unroll
    for (int r = 0; r < 4; ++r) {
      const int m2 = mbase + r;
      const int isres = (m2 < 256);            // uniform per wave (w<4)
      const int crow = isres ? m2 : m2 - 256;
      const float* ap = (isres ? x : skips) + ((size_t)(bb * C_ + crow)) * T_ + t0 + 2;
      float* dp = (isres ? out0 : out3) + ((size_t)(bb * C_ + crow)) * TOUT + t0;
      const float bs = b4[r];
#pragma unroll
      for (int ni = 0; ni < 4; ++ni) {
        int n = ni * 16 + ln;
        if (n < valid) dp[n] = acc2[mi][ni][r] + bs + ap[n];
      }
    }
  }
}

extern "C" void kernel_launch(void* const* d_in, const int* in_sizes, int n_in,
                              void* d_out, int out_size, void* d_ws, size_t ws_size,
                              hipStream_t stream) {
  const float* xx    = (const float*)d_in[0];
  const float* cin   = (const float*)d_in[1];
  const float* gin   = (const float*)d_in[2];
  const float* skips = (const float*)d_in[3];
  const float* w_fx = (const float*)d_in[4],  *b_fx = (const float*)d_in[5];
  const float* w_fc = (const float*)d_in[6],  *b_fc = (const float*)d_in[7];
  const float* w_fg = (const float*)d_in[8],  *b_fg = (const float*)d_in[9];
  const float* w_gx = (const float*)d_in[10], *b_gx = (const float*)d_in[11];
  const float* w_gc = (const float*)d_in[12], *b_gc = (const float*)d_in[13];
  const float* w_gg = (const float*)d_in[14], *b_gg = (const float*)d_in[15];
  const float* w_res  = (const float*)d_in[16], *b_res  = (const float*)d_in[17];
  const float* w_skip = (const float*)d_in[18], *b_skip = (const float*)d_in[19];
  char* ws = (char*)d_ws;
  float* outp = (float*)d_out;

  prep_kernel<<<(N_W1 + N_W2 + 1024) / 256, 256, 0, stream>>>(
      w_fx, w_fc, w_fg, w_gx, w_gc, w_gg,
      b_fx, b_fc, b_fg, b_gx, b_gc, b_gg,
      w_res, b_res, w_skip, b_skip, ws);

  // 8 batches x 128 time-tiles of 64
  wavenet_kernel<<<1024, 512, 0, stream>>>(xx, cin, gin, skips, ws, outp);
}